// Round 3
// baseline (357.616 us; speedup 1.0000x reference)
//
#include <hip/hip_runtime.h>

// DifferentiableTMO: per-batch piecewise-linear CRF LUT over 8x3x1080x1920 fp32.
// HBM floor: 199MB read + 199MB write ~= 63us @6.3TB/s (measured copy ceiling).
// R4 (resubmit; R2 bench was an infra timeout, kernel never measured):
//     explicit depth-2 register pipeline. R3 post-mortem: VGPR=20 proves the
//     compiler serialized load->use->store per float4; in-order vmcnt then
//     couples each iteration's first load-consume to the PREVIOUS iteration's
//     nt-store retirement -> ~50K-cycle stalls/wave/iter, nothing saturated.
//     Now: prefetch next 4 float4 (clamped addrs, no divergence) BEFORE
//     computing/storing current 4, so consuming group k tolerates 8
//     outstanding VMEM ops (4 stores + 4 prefetch loads) and stores never
//     gate progress. Costs ~48 VGPR (still <=64 -> 8 waves/SIMD).

#define KS 256          // CRF sample points
#define NB 25           // PCA basis curves
#define M_BINS 2048     // bucket bins over [0,1)
#define BINS_PER_THR (M_BINS / 256)   // 8
#define NPIX_PER_B 6220800            // 3*1080*1920
#define NP4 (NPIX_PER_B / 4)          // 1555200 float4 per batch

#define SENTINEL 0xFFFFFFFFu          // negative NaN; real slopes are finite

typedef float nvec4 __attribute__((ext_vector_type(4)));   // native vector for nt-store

__device__ __forceinline__ void nt_store4(float4* dst, float4 v)
{
    __builtin_nontemporal_store(*(const nvec4*)&v, (nvec4*)dst);
}

__device__ __forceinline__ float interp_one(float x,
                                            const float* __restrict__ sE,
                                            const float2* __restrict__ sSeg,
                                            const float2* __restrict__ sBin)
{
    // x in [0,1): m = floor(x*2048) exact (x*2^11 is an exponent shift)
    int m = (int)(x * (float)M_BINS);
    m = (m > M_BINS - 1) ? (M_BINS - 1) : m;
    float2 sg = sBin[m];               // single ds_read_b64 on the common path
    if (__builtin_expect(__float_as_uint(sg.x) == SENTINEL, 0)) {
        unsigned int pk = __float_as_uint(sg.y);
        unsigned int j  = pk & 0x1FFu;     // upper_bound(E, bin_start)
        unsigned int c  = pk >> 9;         // breakpoints inside this bin
        while (c) {
            if (sE[j] > x) break;
            ++j; --c;
        }
        sg = sSeg[j];
    }
    float y = fmaf(sg.x, x, sg.y);
    return fminf(fmaxf(y, 0.0f), 1.0f);
}

__device__ __forceinline__ float4 interp_vec(float4 p,
                                             const float* __restrict__ sE,
                                             const float2* __restrict__ sSeg,
                                             const float2* __restrict__ sBin)
{
    float4 r;
    r.x = interp_one(p.x, sE, sSeg, sBin);
    r.y = interp_one(p.y, sE, sSeg, sBin);
    r.z = interp_one(p.z, sE, sSeg, sBin);
    r.w = interp_one(p.w, sE, sSeg, sBin);
    return r;
}

__global__ __launch_bounds__(256, 8)
void tmo_lut_kernel(const float* __restrict__ hdr,
                    const float* __restrict__ w,
                    const float* __restrict__ E,
                    const float* __restrict__ f0,
                    const float* __restrict__ Hb,
                    float* __restrict__ out)
{
    __shared__ float  sE[KS];                     // 1 KB
    __shared__ float2 sSeg[KS + 1];               // 2056 B
    __shared__ float2 sBin[M_BINS];               // 16 KB

    float* sC = (float*)sBin;                     // overlay: sC dead after sSeg built

    const int tid = threadIdx.x;
    const int b   = blockIdx.y;

    // ---- stage E, per-batch curve ----
    sE[tid] = E[tid];
    {
        float acc = f0[tid];
        const float* wb = w + b * NB;   // block-uniform -> scalar loads
        const float* hb = Hb + tid * NB;
        #pragma unroll
        for (int n = 0; n < NB; ++n) acc = fmaf(hb[n], wb[n], acc);
        sC[tid] = acc;
    }
    __syncthreads();

    // ---- segment table ----
    if (tid == 0) {
        sSeg[0]  = make_float2(0.0f, sC[0]);
        sSeg[KS] = make_float2(0.0f, sC[KS - 1]);
    } else {
        float e0 = sE[tid - 1], e1 = sE[tid];
        float c0 = sC[tid - 1], c1 = sC[tid];
        float sl = (c1 - c0) / (e1 - e0);
        float bi = fmaf(-sl, e0, c0);
        sSeg[tid] = make_float2(sl, bi);
    }
    __syncthreads();                               // sC dead after this point

    // ---- direct bin table ----
    {
        const float h = 1.0f / (float)M_BINS;
        int m0 = tid * BINS_PER_THR;
        float v0 = (float)m0 * h;
        int lo = 0, hi = KS;
        while (lo < hi) {
            int mid = (lo + hi) >> 1;
            if (sE[mid] <= v0) lo = mid + 1; else hi = mid;
        }
        int j = lo;
        #pragma unroll
        for (int t = 0; t < BINS_PER_THR; ++t) {
            int m = m0 + t;
            float vn = (float)(m + 1) * h;
            int jn = j;
            while (jn < KS && sE[jn] <= vn) ++jn;
            int c = jn - j;
            float2 e;
            if (c == 0) {
                e = sSeg[j];
            } else {
                e.x = __uint_as_float(SENTINEL);
                e.y = __uint_as_float((unsigned)j | ((unsigned)c << 9));
            }
            sBin[m] = e;
            j = jn;
        }
    }
    __syncthreads();

    // ---- streaming loop: depth-2 register pipeline over groups of 4 float4 ----
    const float4* __restrict__ in4 = (const float4*)(hdr + (size_t)b * NPIX_PER_B);
    float4*                   out4 = (float4*)(out + (size_t)b * NPIX_PER_B);

    const int S  = gridDim.x * blockDim.x;         // 65536
    const int i0 = blockIdx.x * blockDim.x + tid;

    // per-thread element count n = # of k with i0 + k*S < NP4
    const int n   = (NP4 - 1 - i0) / S + 1;        // 23 or 24
    const int G   = n >> 2;                        // full groups of 4
    const int rem = n & 3;                         // 0..3 leftover

    if (G > 0) {
        int idx = i0;
        // prologue: load group 0
        float4 na = in4[idx];
        float4 nb = in4[idx + S];
        float4 nc = in4[idx + 2 * S];
        float4 nd = in4[idx + 3 * S];

        for (int g = 0; g < G; ++g) {
            float4 ca = na, cb = nb, cc = nc, cd = nd;
            int nidx = idx + 4 * S;

            // prefetch group g+1 BEFORE any store of group g.
            // clamped addresses: always in-bounds, wave-uniform control flow;
            // last iteration's prefetch is discarded (harmless L1 hits).
            {
                int a0 = nidx;             a0 = (a0 < NP4) ? a0 : (NP4 - 1);
                int a1 = nidx + S;         a1 = (a1 < NP4) ? a1 : (NP4 - 1);
                int a2 = nidx + 2 * S;     a2 = (a2 < NP4) ? a2 : (NP4 - 1);
                int a3 = nidx + 3 * S;     a3 = (a3 < NP4) ? a3 : (NP4 - 1);
                na = in4[a0];
                nb = in4[a1];
                nc = in4[a2];
                nd = in4[a3];
            }

            // compute + store current group (stores issue AFTER next loads,
            // so the next iteration's consume-wait tolerates them outstanding)
            nt_store4(&out4[idx],         interp_vec(ca, sE, sSeg, sBin));
            nt_store4(&out4[idx + S],     interp_vec(cb, sE, sSeg, sBin));
            nt_store4(&out4[idx + 2 * S], interp_vec(cc, sE, sSeg, sBin));
            nt_store4(&out4[idx + 3 * S], interp_vec(cd, sE, sSeg, sBin));

            idx = nidx;
        }
        // epilogue tail: 0..3 remaining float4
        for (int t = 0; t < rem; ++t) {
            int a = idx + t * S;
            float4 p = in4[a];
            nt_store4(&out4[a], interp_vec(p, sE, sSeg, sBin));
        }
    } else {
        // (cannot happen with current shapes, kept for safety)
        for (int a = i0; a < NP4; a += S) {
            float4 p = in4[a];
            nt_store4(&out4[a], interp_vec(p, sE, sSeg, sBin));
        }
    }
}

extern "C" void kernel_launch(void* const* d_in, const int* in_sizes, int n_in,
                              void* d_out, int out_size, void* d_ws, size_t ws_size,
                              hipStream_t stream)
{
    const float* hdr = (const float*)d_in[0];  // [8,3,1080,1920]
    const float* w   = (const float*)d_in[1];  // [8,25]
    const float* E   = (const float*)d_in[2];  // [256] sorted
    const float* f0  = (const float*)d_in[3];  // [256]
    const float* Hb  = (const float*)d_in[4];  // [256,25]
    float* out = (float*)d_out;

    dim3 grid(256, 8, 1);   // 2048 blocks = 8 blocks/CU on 256 CUs, 32 waves/CU
    dim3 block(256, 1, 1);
    tmo_lut_kernel<<<grid, block, 0, stream>>>(hdr, w, E, f0, Hb, out);
}